// Round 1
// baseline (1155.718 us; speedup 1.0000x reference)
//
#include <hip/hip_runtime.h>

#define BDIM 2
#define DDIM 128
#define HDIM 128
#define WDIM 128
#define CI 64
#define CO 64
#define NTAPS 27
#define GRID_CELLS (BDIM * DDIM * HDIM * WDIM)

// Scatter point indices into the dense voxel grid (grid pre-memset to -1).
__global__ __launch_bounds__(256) void scatter_kernel(
    const int* __restrict__ coords, int* __restrict__ grid, int n) {
    int i = blockIdx.x * blockDim.x + threadIdx.x;
    if (i >= n) return;
    int4 c = ((const int4*)coords)[i];  // b, z, y, x
    int lin = ((c.x * DDIM + c.y) * HDIM + c.z) * WDIM + c.w;
    grid[lin] = i;
}

// One wave (64 lanes) per point; lane = output channel.
__global__ __launch_bounds__(256) void conv_kernel(
    const float* __restrict__ feats,   // (N, 64)
    const float* __restrict__ weight,  // (64, 3,3,3, 64)
    const float* __restrict__ bias,    // (64,)
    const int* __restrict__ coords,    // (N, 4)
    const int* __restrict__ grid,      // (GRID_CELLS,)
    float* __restrict__ out,           // (N, 64)
    int n) {
    int wave = blockIdx.x * 4 + (threadIdx.x >> 6);
    int lane = threadIdx.x & 63;
    if (wave >= n) return;

    int4 c = ((const int4*)coords)[wave];  // b, z, y, x (wave-uniform)
    float acc = bias[lane];

    // Lanes 0..26 probe the 27 neighbor cells in parallel.
    int my_nidx = -1;
    if (lane < NTAPS) {
        int nz = c.y + lane / 9 - 1;
        int ny = c.z + (lane / 3) % 3 - 1;
        int nx = c.w + lane % 3 - 1;
        if (nz >= 0 && nz < DDIM && ny >= 0 && ny < HDIM && nx >= 0 && nx < WDIM) {
            my_nidx = grid[((c.x * DDIM + nz) * HDIM + ny) * WDIM + nx];
        }
    }

    for (int tap = 0; tap < NTAPS; ++tap) {
        int nidx = __shfl(my_nidx, tap);  // wave-uniform
        if (nidx < 0) continue;           // uniform branch, no divergence
        const float4* grow = (const float4*)(feats + (size_t)nidx * CI);
        const float4* wrow = (const float4*)(weight + (size_t)lane * (NTAPS * CI) + tap * CI);
#pragma unroll 8
        for (int ci4 = 0; ci4 < CI / 4; ++ci4) {
            float4 g = grow[ci4];  // same addr across lanes -> L1 broadcast
            float4 w = wrow[ci4];  // per-lane weight row
            acc += g.x * w.x + g.y * w.y + g.z * w.z + g.w * w.w;
        }
    }

    out[(size_t)wave * CO + lane] = acc;
}

extern "C" void kernel_launch(void* const* d_in, const int* in_sizes, int n_in,
                              void* d_out, int out_size, void* d_ws, size_t ws_size,
                              hipStream_t stream) {
    const float* feats  = (const float*)d_in[0];
    const float* weight = (const float*)d_in[1];
    const float* bias   = (const float*)d_in[2];
    const int*   coords = (const int*)d_in[3];
    float* out = (float*)d_out;
    int n = in_sizes[3] / 4;

    int* grid = (int*)d_ws;  // 16 MB dense voxel hash

    hipMemsetAsync(grid, 0xFF, (size_t)GRID_CELLS * sizeof(int), stream);
    scatter_kernel<<<(n + 255) / 256, 256, 0, stream>>>(coords, grid, n);
    conv_kernel<<<(n + 3) / 4, 256, 0, stream>>>(feats, weight, bias, coords, grid, out, n);
}

// Round 2
// 510.673 us; speedup vs baseline: 2.2631x; 2.2631x over previous
//
#include <hip/hip_runtime.h>

#define BDIM 2
#define DDIM 128
#define HDIM 128
#define WDIM 128
#define CI 64
#define CO 64
#define NTAPS 27
#define GRID_CELLS (BDIM * DDIM * HDIM * WDIM)
#define WT_ELEMS (NTAPS * 16 * CO)  // float4 elements in transposed weight

// ws layout: [0, 512KB) transposed weight float4[27][16][64]; [512KB, +16MB) voxel grid

__global__ __launch_bounds__(256) void scatter_kernel(
    const int* __restrict__ coords, int* __restrict__ grid, int n) {
    int i = blockIdx.x * blockDim.x + threadIdx.x;
    if (i >= n) return;
    int4 c = ((const int4*)coords)[i];  // b, z, y, x
    int lin = ((c.x * DDIM + c.y) * HDIM + c.z) * WDIM + c.w;
    grid[lin] = i;
}

// w_t[(tap*16 + ci4)*64 + o] = weight[o][tap][ci4*4 .. +3]
__global__ __launch_bounds__(256) void transpose_w_kernel(
    const float* __restrict__ weight, float4* __restrict__ wt) {
    int idx = blockIdx.x * blockDim.x + threadIdx.x;
    if (idx >= WT_ELEMS) return;
    int o   = idx & 63;
    int ci4 = (idx >> 6) & 15;
    int tap = idx >> 10;
    wt[idx] = *(const float4*)(weight + ((size_t)o * NTAPS + tap) * CI + ci4 * 4);
}

// One wave per point; lane = output channel.
__global__ __launch_bounds__(256) void conv_kernel(
    const float* __restrict__ feats,    // (N, 64)
    const float4* __restrict__ wt,      // (27, 16, 64) float4
    const float* __restrict__ bias,     // (64,)
    const int* __restrict__ coords,     // (N, 4)
    const int* __restrict__ grid,       // (GRID_CELLS,)
    float* __restrict__ out,            // (N, 64)
    int n) {
    int wave = blockIdx.x * 4 + (threadIdx.x >> 6);
    int lane = threadIdx.x & 63;
    if (wave >= n) return;

    int4 c = ((const int4*)coords)[wave];  // b, z, y, x (wave-uniform)

    // Lanes 0..26 probe the 27 neighbor cells in parallel.
    int my_nidx = -1;
    if (lane < NTAPS) {
        int nz = c.y + lane / 9 - 1;
        int ny = c.z + (lane / 3) % 3 - 1;
        int nx = c.w + lane % 3 - 1;
        if (nz >= 0 && nz < DDIM && ny >= 0 && ny < HDIM && nx >= 0 && nx < WDIM) {
            my_nidx = grid[((c.x * DDIM + nz) * HDIM + ny) * WDIM + nx];
        }
    }

    float4 acc = {0.f, 0.f, 0.f, 0.f};  // 4 independent FMA chains
    for (int tap = 0; tap < NTAPS; ++tap) {
        int nidx = __shfl(my_nidx, tap);  // wave-uniform
        if (nidx < 0) continue;           // uniform branch
        const float4* grow = (const float4*)(feats + (size_t)nidx * CI);
        const float4* wrow = wt + tap * (16 * CO) + lane;
#pragma unroll
        for (int ci4 = 0; ci4 < 16; ++ci4) {
            float4 g = grow[ci4];        // same addr across lanes -> broadcast
            float4 w = wrow[ci4 * CO];   // lane-consecutive float4 -> coalesced
            acc.x += g.x * w.x;
            acc.y += g.y * w.y;
            acc.z += g.z * w.z;
            acc.w += g.w * w.w;
        }
    }

    out[(size_t)wave * CO + lane] = acc.x + acc.y + acc.z + acc.w + bias[lane];
}

extern "C" void kernel_launch(void* const* d_in, const int* in_sizes, int n_in,
                              void* d_out, int out_size, void* d_ws, size_t ws_size,
                              hipStream_t stream) {
    const float* feats  = (const float*)d_in[0];
    const float* weight = (const float*)d_in[1];
    const float* bias   = (const float*)d_in[2];
    const int*   coords = (const int*)d_in[3];
    float* out = (float*)d_out;
    int n = in_sizes[3] / 4;

    float4* wt = (float4*)d_ws;
    int* grid = (int*)((char*)d_ws + (size_t)(512 * 1024));

    hipMemsetAsync(grid, 0xFF, (size_t)GRID_CELLS * sizeof(int), stream);
    scatter_kernel<<<(n + 255) / 256, 256, 0, stream>>>(coords, grid, n);
    transpose_w_kernel<<<(WT_ELEMS + 255) / 256, 256, 0, stream>>>(weight, wt);
    conv_kernel<<<(n + 3) / 4, 256, 0, stream>>>(feats, wt, bias, coords, grid, out, n);
}

// Round 3
// 319.246 us; speedup vs baseline: 3.6201x; 1.5996x over previous
//
#include <hip/hip_runtime.h>

#define BDIM 2
#define DDIM 128
#define HDIM 128
#define WDIM 128
#define CI 64
#define CO 64
#define NTAPS 27
#define GRID_CELLS (BDIM * DDIM * HDIM * WDIM)
#define CAP 16384        // rulebook capacity per non-center tap (expected ~9.5k)
#define CNT_STRIDE 32    // pad counters to 128 B to avoid cacheline contention

typedef __attribute__((ext_vector_type(8))) short short8;
typedef __attribute__((ext_vector_type(4))) float floatx4;

// ws layout:
//   [0, 16 MB)            voxel grid (int)
//   [16 MB, +256 KB)      wt_frag: short8[27*2*4*64]  (B-fragments, bf16 bits)
//   [+4 KB)               cnt: int[27*CNT_STRIDE]
//   [+3.5 MB)             rb: int2[27*CAP]
#define GRID_BYTES (16777216)
#define WT_OFF GRID_BYTES
#define CNT_OFF (WT_OFF + 262144)
#define RB_OFF (CNT_OFF + 4096)

__device__ __forceinline__ unsigned short f2bf(float f) {
    unsigned int u = __float_as_uint(f);
    return (unsigned short)((u + 0x7FFFu + ((u >> 16) & 1u)) >> 16);  // RNE
}

__global__ __launch_bounds__(256) void scatter_kernel(
    const int* __restrict__ coords, int* __restrict__ grid, int n) {
    int i = blockIdx.x * blockDim.x + threadIdx.x;
    if (i >= n) return;
    int4 c = ((const int4*)coords)[i];  // b, z, y, x
    grid[((c.x * DDIM + c.y) * HDIM + c.z) * WDIM + c.w] = i;
}

// Pack weight (CO,3,3,3,CI) into MFMA B-fragment layout, bf16:
// wt8[((t*2+s)*4+ot)*64 + l][j] = W[ot*16+(l&15)][t][s*32+(l>>4)*8+j]
__global__ __launch_bounds__(256) void wfrag_kernel(
    const float* __restrict__ weight, short8* __restrict__ wt8) {
    int idx = blockIdx.x * blockDim.x + threadIdx.x;
    if (idx >= NTAPS * 2 * 4 * 64) return;
    int l = idx & 63, ot = (idx >> 6) & 3, s = (idx >> 8) & 1, t = idx >> 9;
    int o = ot * 16 + (l & 15);
    int k0 = s * 32 + ((l >> 4) << 3);
    const float* src = weight + ((size_t)o * NTAPS + t) * CI + k0;
    short8 v;
#pragma unroll
    for (int j = 0; j < 8; ++j) v[j] = (short)f2bf(src[j]);
    wt8[idx] = v;
}

__global__ __launch_bounds__(256) void bias_init_kernel(
    const float* __restrict__ bias, float4* __restrict__ out4, int n16) {
    int i = blockIdx.x * blockDim.x + threadIdx.x;
    if (i >= n16) return;
    out4[i] = ((const float4*)bias)[i & 15];
}

// One wave per point; lanes 0..26 (skip center 13) probe and append entries.
__global__ __launch_bounds__(256) void build_kernel(
    const int* __restrict__ coords, const int* __restrict__ grid,
    int2* __restrict__ rb, int* __restrict__ cnt, int n) {
    int wave = blockIdx.x * 4 + (threadIdx.x >> 6);
    int lane = threadIdx.x & 63;
    if (wave >= n || lane >= NTAPS || lane == 13) return;
    int4 c = ((const int4*)coords)[wave];
    int nz = c.y + lane / 9 - 1;
    int ny = c.z + (lane / 3) % 3 - 1;
    int nx = c.w + lane % 3 - 1;
    if (nz < 0 || nz >= DDIM || ny < 0 || ny >= HDIM || nx < 0 || nx >= WDIM) return;
    int nidx = grid[((c.x * DDIM + nz) * HDIM + ny) * WDIM + nx];
    if (nidx < 0) return;
    int slot = atomicAdd(&cnt[lane * CNT_STRIDE], 1);
    if (slot < CAP) rb[(size_t)lane * CAP + slot] = make_int2(nidx, wave);
}

// Per-tap gather-GEMM. Block = 4 waves; each wave: 16 entries (M=16, N=64, K=64).
// Tap 13 (center) uses implicit identity entries (nidx = pt = row).
__global__ __launch_bounds__(256) void gemm_kernel(
    const float* __restrict__ feats, const short8* __restrict__ wt8,
    const int2* __restrict__ rb, const int* __restrict__ cnt,
    float* __restrict__ out, int n) {
    int tap = blockIdx.y;
    int count = (tap == 13) ? n : cnt[tap * CNT_STRIDE];
    int base = blockIdx.x * 64 + ((threadIdx.x >> 6) << 4);
    if (base >= count) return;
    int l = threadIdx.x & 63;
    int r0 = l & 15, quad = l >> 4;
    int mcount = count - base;
    if (mcount > 16) mcount = 16;

    int er = base + (r0 < mcount ? r0 : mcount - 1);  // clamp padding rows
    int2 e = (tap == 13) ? make_int2(er, er) : rb[(size_t)tap * CAP + er];

    // A-fragments: lane holds A[m=l&15][k=quad*8+j] for K-steps s=0,1
    const float* arow = feats + (size_t)e.x * CI + quad * 8;
    float4 a0 = *(const float4*)(arow);
    float4 a1 = *(const float4*)(arow + 4);
    float4 a2 = *(const float4*)(arow + 32);
    float4 a3 = *(const float4*)(arow + 36);
    short8 af0, af1;
    af0[0] = (short)f2bf(a0.x); af0[1] = (short)f2bf(a0.y);
    af0[2] = (short)f2bf(a0.z); af0[3] = (short)f2bf(a0.w);
    af0[4] = (short)f2bf(a1.x); af0[5] = (short)f2bf(a1.y);
    af0[6] = (short)f2bf(a1.z); af0[7] = (short)f2bf(a1.w);
    af1[0] = (short)f2bf(a2.x); af1[1] = (short)f2bf(a2.y);
    af1[2] = (short)f2bf(a2.z); af1[3] = (short)f2bf(a2.w);
    af1[4] = (short)f2bf(a3.x); af1[5] = (short)f2bf(a3.y);
    af1[6] = (short)f2bf(a3.z); af1[7] = (short)f2bf(a3.w);

    // B-fragments for this tap (reused across the wave's 16 entries)
    const short8* wb = wt8 + (size_t)tap * 8 * 64;
    floatx4 acc0 = {0.f, 0.f, 0.f, 0.f}, acc1 = acc0, acc2 = acc0, acc3 = acc0;
    acc0 = __builtin_amdgcn_mfma_f32_16x16x32_bf16(af0, wb[0 * 64 + l], acc0, 0, 0, 0);
    acc1 = __builtin_amdgcn_mfma_f32_16x16x32_bf16(af0, wb[1 * 64 + l], acc1, 0, 0, 0);
    acc2 = __builtin_amdgcn_mfma_f32_16x16x32_bf16(af0, wb[2 * 64 + l], acc2, 0, 0, 0);
    acc3 = __builtin_amdgcn_mfma_f32_16x16x32_bf16(af0, wb[3 * 64 + l], acc3, 0, 0, 0);
    acc0 = __builtin_amdgcn_mfma_f32_16x16x32_bf16(af1, wb[4 * 64 + l], acc0, 0, 0, 0);
    acc1 = __builtin_amdgcn_mfma_f32_16x16x32_bf16(af1, wb[5 * 64 + l], acc1, 0, 0, 0);
    acc2 = __builtin_amdgcn_mfma_f32_16x16x32_bf16(af1, wb[6 * 64 + l], acc2, 0, 0, 0);
    acc3 = __builtin_amdgcn_mfma_f32_16x16x32_bf16(af1, wb[7 * 64 + l], acc3, 0, 0, 0);

    // C layout: col = l&15, row = quad*4 + reg. Scatter-add valid rows.
#pragma unroll
    for (int r = 0; r < 4; ++r) {
        int m = quad * 4 + r;
        int pt = __shfl(e.y, m);  // lane m holds row m's entry
        if (m < mcount) {
            float* orow = out + (size_t)pt * CO + r0;
            atomicAdd(orow + 0, acc0[r]);
            atomicAdd(orow + 16, acc1[r]);
            atomicAdd(orow + 32, acc2[r]);
            atomicAdd(orow + 48, acc3[r]);
        }
    }
}

extern "C" void kernel_launch(void* const* d_in, const int* in_sizes, int n_in,
                              void* d_out, int out_size, void* d_ws, size_t ws_size,
                              hipStream_t stream) {
    const float* feats  = (const float*)d_in[0];
    const float* weight = (const float*)d_in[1];
    const float* bias   = (const float*)d_in[2];
    const int*   coords = (const int*)d_in[3];
    float* out = (float*)d_out;
    int n = in_sizes[3] / 4;

    int*    grid = (int*)d_ws;
    short8* wt8  = (short8*)((char*)d_ws + WT_OFF);
    int*    cnt  = (int*)((char*)d_ws + CNT_OFF);
    int2*   rb   = (int2*)((char*)d_ws + RB_OFF);

    hipMemsetAsync(grid, 0xFF, (size_t)GRID_CELLS * sizeof(int), stream);
    hipMemsetAsync(cnt, 0, NTAPS * CNT_STRIDE * sizeof(int), stream);
    scatter_kernel<<<(n + 255) / 256, 256, 0, stream>>>(coords, grid, n);
    wfrag_kernel<<<(NTAPS * 2 * 4 * 64 + 255) / 256, 256, 0, stream>>>(weight, wt8);
    bias_init_kernel<<<(n * 16 + 255) / 256, 256, 0, stream>>>(bias, (float4*)out, n * 16);
    build_kernel<<<(n + 3) / 4, 256, 0, stream>>>(coords, grid, rb, cnt, n);
    dim3 gg((n + 63) / 64, NTAPS);
    gemm_kernel<<<gg, 256, 0, stream>>>(feats, wt8, rb, cnt, out, n);
}

// Round 4
// 207.860 us; speedup vs baseline: 5.5601x; 1.5359x over previous
//
#include <hip/hip_runtime.h>
#include <hip/hip_bf16.h>

#define BDIM 2
#define DDIM 128
#define HDIM 128
#define WDIM 128
#define CI 64
#define CO 64
#define NTAPS 27
#define GRID_CELLS (BDIM * DDIM * HDIM * WDIM)

typedef __attribute__((ext_vector_type(8))) short short8;
typedef __attribute__((ext_vector_type(4))) float floatx4;

// ws layout: [0, 16 MB) voxel grid (int); [16 MB, +256 KB) wt8 B-fragments
#define GRID_BYTES 16777216
#define WT_OFF GRID_BYTES

__device__ __forceinline__ unsigned short f2bf(float f) {
    unsigned int u = __float_as_uint(f);
    return (unsigned short)((u + 0x7FFFu + ((u >> 16) & 1u)) >> 16);  // RNE
}

__global__ __launch_bounds__(256) void scatter_kernel(
    const int* __restrict__ coords, int* __restrict__ grid, int n) {
    int i = blockIdx.x * blockDim.x + threadIdx.x;
    if (i >= n) return;
    int4 c = ((const int4*)coords)[i];  // b, z, y, x
    grid[((c.x * DDIM + c.y) * HDIM + c.z) * WDIM + c.w] = i;
}

// Pack weight (CO,3,3,3,CI) into MFMA B-fragment layout, bf16:
// wt8[((t*2+s)*4+ot)*64 + l][j] = W[ot*16+(l&15)][t][s*32+(l>>4)*8+j]
__global__ __launch_bounds__(256) void wfrag_kernel(
    const float* __restrict__ weight, short8* __restrict__ wt8) {
    int idx = blockIdx.x * blockDim.x + threadIdx.x;
    if (idx >= NTAPS * 2 * 4 * 64) return;
    int l = idx & 63, ot = (idx >> 6) & 3, s = (idx >> 8) & 1, t = idx >> 9;
    int o = ot * 16 + (l & 15);
    int k0 = s * 32 + ((l >> 4) << 3);
    const float* src = weight + ((size_t)o * NTAPS + t) * CI + k0;
    short8 v;
#pragma unroll
    for (int j = 0; j < 8; ++j) v[j] = (short)f2bf(src[j]);
    wt8[idx] = v;
}

// Output-stationary fused conv: one wave per 16 points.
// Lanes probe all 27*16 neighbor cells (7 instrs), __shfl-transpose to
// tap-major, then per active tap gather A rows and MFMA into 16x64 acc.
__global__ __launch_bounds__(256) void fused_conv_kernel(
    const float* __restrict__ feats,   // (N, 64)
    const short8* __restrict__ wt8,    // B-fragments
    const float* __restrict__ bias,    // (64,)
    const int* __restrict__ coords,    // (N, 4)
    const int* __restrict__ grid,      // (GRID_CELLS,)
    float* __restrict__ out,           // (N, 64)
    int n) {
    int wave = blockIdx.x * 4 + (threadIdx.x >> 6);
    int l = threadIdx.x & 63;
    int quad = l >> 4, m = l & 15;
    int base = wave * 16;
    if (base >= n) return;

    int cpt = base + m;
    if (cpt >= n) cpt = n - 1;           // duplicate last row in tail group
    int4 c = ((const int4*)coords)[cpt]; // b, z, y, x for row m (16 distinct)

    // Probe phase: probe i covers tap t = 4*i + quad for row m.
    int p0, p1, p2, p3, p4, p5, p6;
#pragma unroll
    for (int i = 0; i < 7; ++i) {
        int t = 4 * i + quad;
        int v = -1;
        if (t < NTAPS) {
            int dz = t / 9 - 1, rem = t % 9;
            int dy = rem / 3 - 1, dx = rem % 3 - 1;
            int nz = c.y + dz, ny = c.z + dy, nx = c.w + dx;
            if (nz >= 0 && nz < DDIM && ny >= 0 && ny < HDIM &&
                nx >= 0 && nx < WDIM)
                v = grid[((c.x * DDIM + nz) * HDIM + ny) * WDIM + nx];
        }
        if (i == 0) p0 = v; else if (i == 1) p1 = v; else if (i == 2) p2 = v;
        else if (i == 3) p3 = v; else if (i == 4) p4 = v; else if (i == 5) p5 = v;
        else p6 = v;
    }

    floatx4 acc0 = {0.f, 0.f, 0.f, 0.f}, acc1 = acc0, acc2 = acc0, acc3 = acc0;

#pragma unroll
    for (int t = 0; t < NTAPS; ++t) {
        int src;
        switch (t >> 2) {
            case 0: src = p0; break; case 1: src = p1; break;
            case 2: src = p2; break; case 3: src = p3; break;
            case 4: src = p4; break; case 5: src = p5; break;
            default: src = p6; break;
        }
        int v = __shfl(src, ((t & 3) << 4) | m);  // nidx for (tap t, row m)
        if (__ballot(v >= 0) == 0) continue;      // skip empty tap (uniform)

        float4 x0 = {0.f, 0.f, 0.f, 0.f}, x1 = x0, x2 = x0, x3 = x0;
        if (v >= 0) {
            const float4* ar = (const float4*)(feats + (size_t)v * CI + quad * 8);
            x0 = ar[0]; x1 = ar[1];   // K-step 0: k = quad*8 .. +7
            x2 = ar[8]; x3 = ar[9];   // K-step 1: k = 32 + quad*8 .. +7
        }
        union { short8 s; __hip_bfloat162 h[4]; } af0, af1;
        af0.h[0] = __float22bfloat162_rn({x0.x, x0.y});
        af0.h[1] = __float22bfloat162_rn({x0.z, x0.w});
        af0.h[2] = __float22bfloat162_rn({x1.x, x1.y});
        af0.h[3] = __float22bfloat162_rn({x1.z, x1.w});
        af1.h[0] = __float22bfloat162_rn({x2.x, x2.y});
        af1.h[1] = __float22bfloat162_rn({x2.z, x2.w});
        af1.h[2] = __float22bfloat162_rn({x3.x, x3.y});
        af1.h[3] = __float22bfloat162_rn({x3.z, x3.w});

        const short8* wb = wt8 + (size_t)t * 8 * 64 + l;
        acc0 = __builtin_amdgcn_mfma_f32_16x16x32_bf16(af0.s, wb[0 * 64], acc0, 0, 0, 0);
        acc1 = __builtin_amdgcn_mfma_f32_16x16x32_bf16(af0.s, wb[1 * 64], acc1, 0, 0, 0);
        acc2 = __builtin_amdgcn_mfma_f32_16x16x32_bf16(af0.s, wb[2 * 64], acc2, 0, 0, 0);
        acc3 = __builtin_amdgcn_mfma_f32_16x16x32_bf16(af0.s, wb[3 * 64], acc3, 0, 0, 0);
        acc0 = __builtin_amdgcn_mfma_f32_16x16x32_bf16(af1.s, wb[4 * 64], acc0, 0, 0, 0);
        acc1 = __builtin_amdgcn_mfma_f32_16x16x32_bf16(af1.s, wb[5 * 64], acc1, 0, 0, 0);
        acc2 = __builtin_amdgcn_mfma_f32_16x16x32_bf16(af1.s, wb[6 * 64], acc2, 0, 0, 0);
        acc3 = __builtin_amdgcn_mfma_f32_16x16x32_bf16(af1.s, wb[7 * 64], acc3, 0, 0, 0);
    }

    // C layout: channel col = m, point row = quad*4 + reg. Bias + store once.
    float b0 = bias[m], b1 = bias[m + 16], b2 = bias[m + 32], b3 = bias[m + 48];
#pragma unroll
    for (int r = 0; r < 4; ++r) {
        int pt = base + quad * 4 + r;
        if (pt < n) {
            float* orow = out + (size_t)pt * CO;
            orow[m]      = acc0[r] + b0;
            orow[m + 16] = acc1[r] + b1;
            orow[m + 32] = acc2[r] + b2;
            orow[m + 48] = acc3[r] + b3;
        }
    }
}

extern "C" void kernel_launch(void* const* d_in, const int* in_sizes, int n_in,
                              void* d_out, int out_size, void* d_ws, size_t ws_size,
                              hipStream_t stream) {
    const float* feats  = (const float*)d_in[0];
    const float* weight = (const float*)d_in[1];
    const float* bias   = (const float*)d_in[2];
    const int*   coords = (const int*)d_in[3];
    float* out = (float*)d_out;
    int n = in_sizes[3] / 4;

    int*    grid = (int*)d_ws;
    short8* wt8  = (short8*)((char*)d_ws + WT_OFF);

    hipMemsetAsync(grid, 0xFF, (size_t)GRID_CELLS * sizeof(int), stream);
    scatter_kernel<<<(n + 255) / 256, 256, 0, stream>>>(coords, grid, n);
    wfrag_kernel<<<(NTAPS * 2 * 4 * 64 + 255) / 256, 256, 0, stream>>>(weight, wt8);
    int waves = (n + 15) / 16;
    fused_conv_kernel<<<(waves + 3) / 4, 256, 0, stream>>>(
        feats, wt8, bias, coords, grid, out, n);
}

// Round 6
// 195.829 us; speedup vs baseline: 5.9017x; 1.0614x over previous
//
#include <hip/hip_runtime.h>
#include <hip/hip_bf16.h>

#define BDIM 2
#define DDIM 128
#define HDIM 128
#define WDIM 128
#define CI 64
#define CO 64
#define NTAPS 27
#define GRID_CELLS (BDIM * DDIM * HDIM * WDIM)  // 4,194,304
#define NCBLK (GRID_CELLS / 256)                // 16384

typedef __attribute__((ext_vector_type(8))) short short8;
typedef __attribute__((ext_vector_type(4))) float floatx4;

// ws layout:
//   [0, 16 MB)        voxel grid (int)
//   +16 MB:   wt8     B-fragments, 256 KB
//   +16.25MB: bcnt    int[16384] block counts -> exclusive offsets (in place)
//   +~16.3MB: order   int[N] spatially-sorted point indices
#define WT_OFF   ((size_t)16 << 20)
#define BCNT_OFF (WT_OFF + ((size_t)256 << 10))
#define ORD_OFF  (BCNT_OFF + ((size_t)64 << 10))

__device__ __forceinline__ unsigned short f2bf(float f) {
    unsigned int u = __float_as_uint(f);
    return (unsigned short)((u + 0x7FFFu + ((u >> 16) & 1u)) >> 16);  // RNE
}

__global__ __launch_bounds__(256) void scatter_kernel(
    const int* __restrict__ coords, int* __restrict__ grid, int n) {
    int i = blockIdx.x * blockDim.x + threadIdx.x;
    if (i >= n) return;
    int4 c = ((const int4*)coords)[i];  // b, z, y, x
    grid[((c.x * DDIM + c.y) * HDIM + c.z) * WDIM + c.w] = i;
}

// Pack weight (CO,3,3,3,CI) into MFMA B-fragment layout, bf16:
// wt8[t*512 + (s*4+ot)*64 + l][j] = W[ot*16+(l&15)][t][s*32+(l>>4)*8+j]
__global__ __launch_bounds__(256) void wfrag_kernel(
    const float* __restrict__ weight, short8* __restrict__ wt8) {
    int idx = blockIdx.x * blockDim.x + threadIdx.x;
    if (idx >= NTAPS * 2 * 4 * 64) return;
    int l = idx & 63, ot = (idx >> 6) & 3, s = (idx >> 8) & 1, t = idx >> 9;
    int o = ot * 16 + (l & 15);
    int k0 = s * 32 + ((l >> 4) << 3);
    const float* src = weight + ((size_t)o * NTAPS + t) * CI + k0;
    short8 v;
#pragma unroll
    for (int j = 0; j < 8; ++j) v[j] = (short)f2bf(src[j]);
    wt8[idx] = v;
}

// ---- grid stream-compaction (spatial sort for free) ----
__global__ __launch_bounds__(256) void count_kernel(
    const int* __restrict__ grid, int* __restrict__ bcnt) {
    int i = blockIdx.x * 256 + threadIdx.x;
    unsigned long long b = __ballot(grid[i] >= 0);
    __shared__ int wc[4];
    if ((threadIdx.x & 63) == 0) wc[threadIdx.x >> 6] = __popcll(b);
    __syncthreads();
    if (threadIdx.x == 0) bcnt[blockIdx.x] = wc[0] + wc[1] + wc[2] + wc[3];
}

__global__ __launch_bounds__(1024) void scan_kernel(int* __restrict__ bcnt) {
    __shared__ int part[1024];
    int tid = threadIdx.x;
    int v[16], s = 0;
#pragma unroll
    for (int k = 0; k < 16; ++k) { v[k] = bcnt[tid * 16 + k]; s += v[k]; }
    part[tid] = s;
    __syncthreads();
    for (int off = 1; off < 1024; off <<= 1) {
        int t = (tid >= off) ? part[tid - off] : 0;
        __syncthreads();
        part[tid] += t;
        __syncthreads();
    }
    int ex = tid ? part[tid - 1] : 0;
#pragma unroll
    for (int k = 0; k < 16; ++k) { int nv = ex; ex += v[k]; bcnt[tid * 16 + k] = nv; }
}

__global__ __launch_bounds__(256) void emit_kernel(
    const int* __restrict__ grid, const int* __restrict__ boff,
    int* __restrict__ order) {
    int i = blockIdx.x * 256 + threadIdx.x;
    int v = grid[i];
    int lane = threadIdx.x & 63, w = threadIdx.x >> 6;
    unsigned long long b = __ballot(v >= 0);
    __shared__ int wc[4];
    if (lane == 0) wc[w] = __popcll(b);
    __syncthreads();
    int woff = 0;
    for (int k = 0; k < w; ++k) woff += wc[k];
    if (v >= 0) {
        int rank = __popcll(b & ((1ull << lane) - 1ull));
        order[boff[blockIdx.x] + woff + rank] = v;
    }
}

// ---- fused conv: block = 64 sorted points (4 waves x 16 rows) ----
// Per tap: B-frag staged once to LDS (triple buffer, 1 barrier/tap) shared by
// 4 waves; A rows gathered with depth-2 prefetch across taps.
__global__ __launch_bounds__(256) void conv_kernel(
    const float* __restrict__ feats, const short8* __restrict__ wt8,
    const float* __restrict__ bias, const int* __restrict__ coords,
    const int* __restrict__ grid, const int* __restrict__ order,
    float* __restrict__ out, int n) {
    __shared__ short8 bs[3][512];  // 24 KB
    int tid = threadIdx.x;
    int w = tid >> 6, l = tid & 63, quad = l >> 4, m = l & 15;
    int jrow = blockIdx.x * 64 + w * 16 + m;
    int j = jrow < n ? jrow : n - 1;
    int p = order[j];
    int4 c = ((const int4*)coords)[p];

    // Probe phase: probe i covers tap t = 4*i + quad for row m.
    int pr[7];
#pragma unroll
    for (int i = 0; i < 7; ++i) {
        int t = 4 * i + quad;
        int v = -1;
        if (t < NTAPS) {
            int dz = t / 9 - 1, rem = t % 9;
            int dy = rem / 3 - 1, dx = rem % 3 - 1;
            int nz = c.y + dz, ny = c.z + dy, nx = c.w + dx;
            if (nz >= 0 && nz < DDIM && ny >= 0 && ny < HDIM &&
                nx >= 0 && nx < WDIM)
                v = grid[((c.x * DDIM + nz) * HDIM + ny) * WDIM + nx];
        }
        pr[i] = v;
    }

    floatx4 acc0 = {0.f, 0.f, 0.f, 0.f}, acc1 = acc0, acc2 = acc0, acc3 = acc0;
    float4 xA[4], xB[4];
    int vA = -1, vB = -1;

    // stage tap t's 8KB B-frag into bs[t%3]; 2 short8 per thread
#define STAGE(t)                                                     \
    {                                                                \
        const short8* src = wt8 + (size_t)(t) * 512 + tid * 2;       \
        short8 s0 = src[0], s1 = src[1];                             \
        bs[(t) % 3][tid * 2] = s0;                                   \
        bs[(t) % 3][tid * 2 + 1] = s1;                               \
    }

#define GATHER(t, g, vv)                                             \
    {                                                                \
        int vsrc = pr[(t) >> 2];                                     \
        vv = __shfl(vsrc, (((t) & 3) << 4) | m);                     \
        g[0] = g[1] = g[2] = g[3] = float4{0.f, 0.f, 0.f, 0.f};      \
        if (vv >= 0) {                                               \
            const float4* ar =                                       \
                (const float4*)(feats + (size_t)vv * CI + quad * 8); \
            g[0] = ar[0]; g[1] = ar[1]; g[2] = ar[8]; g[3] = ar[9];  \
        }                                                            \
    }

#define COMPUTE(t, g, vv)                                                          \
    if (__ballot(vv >= 0) != 0ull) {                                               \
        union { short8 s; __hip_bfloat162 h[4]; } f0, f1;                          \
        f0.h[0] = __float22bfloat162_rn({g[0].x, g[0].y});                         \
        f0.h[1] = __float22bfloat162_rn({g[0].z, g[0].w});                         \
        f0.h[2] = __float22bfloat162_rn({g[1].x, g[1].y});                         \
        f0.h[3] = __float22bfloat162_rn({g[1].z, g[1].w});                         \
        f1.h[0] = __float22bfloat162_rn({g[2].x, g[2].y});                         \
        f1.h[1] = __float22bfloat162_rn({g[2].z, g[2].w});                         \
        f1.h[2] = __float22bfloat162_rn({g[3].x, g[3].y});                         \
        f1.h[3] = __float22bfloat162_rn({g[3].z, g[3].w});                         \
        const short8* wb = &bs[(t) % 3][l];                                        \
        acc0 = __builtin_amdgcn_mfma_f32_16x16x32_bf16(f0.s, wb[0 * 64], acc0, 0, 0, 0); \
        acc1 = __builtin_amdgcn_mfma_f32_16x16x32_bf16(f0.s, wb[1 * 64], acc1, 0, 0, 0); \
        acc2 = __builtin_amdgcn_mfma_f32_16x16x32_bf16(f0.s, wb[2 * 64], acc2, 0, 0, 0); \
        acc3 = __builtin_amdgcn_mfma_f32_16x16x32_bf16(f0.s, wb[3 * 64], acc3, 0, 0, 0); \
        acc0 = __builtin_amdgcn_mfma_f32_16x16x32_bf16(f1.s, wb[4 * 64], acc0, 0, 0, 0); \
        acc1 = __builtin_amdgcn_mfma_f32_16x16x32_bf16(f1.s, wb[5 * 64], acc1, 0, 0, 0); \
        acc2 = __builtin_amdgcn_mfma_f32_16x16x32_bf16(f1.s, wb[6 * 64], acc2, 0, 0, 0); \
        acc3 = __builtin_amdgcn_mfma_f32_16x16x32_bf16(f1.s, wb[7 * 64], acc3, 0, 0, 0); \
    }

    STAGE(0);
    GATHER(0, xA, vA);
#pragma unroll
    for (int t = 0; t < NTAPS; ++t) {
        if (t + 1 < NTAPS) {
            STAGE(t + 1);
            if (t & 1) { GATHER(t + 1, xA, vA); } else { GATHER(t + 1, xB, vB); }
        }
        __syncthreads();  // bs[t%3] staged (prev iter) & this iter's loads drain
        if (t & 1) { COMPUTE(t, xB, vB); } else { COMPUTE(t, xA, vA); }
    }

    // C layout: channel col = m, point row = quad*4 + reg.
    float b0 = bias[m], b1 = bias[m + 16], b2 = bias[m + 32], b3 = bias[m + 48];
#pragma unroll
    for (int r = 0; r < 4; ++r) {
        int row = quad * 4 + r;
        int jr = blockIdx.x * 64 + w * 16 + row;
        int prow = __shfl(p, row);  // lane `row` (quad 0) holds row's point idx
        if (jr < n) {
            float* orow = out + (size_t)prow * CO;
            orow[m]      = acc0[r] + b0;
            orow[m + 16] = acc1[r] + b1;
            orow[m + 32] = acc2[r] + b2;
            orow[m + 48] = acc3[r] + b3;
        }
    }
#undef STAGE
#undef GATHER
#undef COMPUTE
}

extern "C" void kernel_launch(void* const* d_in, const int* in_sizes, int n_in,
                              void* d_out, int out_size, void* d_ws, size_t ws_size,
                              hipStream_t stream) {
    const float* feats  = (const float*)d_in[0];
    const float* weight = (const float*)d_in[1];
    const float* bias   = (const float*)d_in[2];
    const int*   coords = (const int*)d_in[3];
    float* out = (float*)d_out;
    int n = in_sizes[3] / 4;

    int*    grid  = (int*)d_ws;
    short8* wt8   = (short8*)((char*)d_ws + WT_OFF);
    int*    bcnt  = (int*)((char*)d_ws + BCNT_OFF);
    int*    order = (int*)((char*)d_ws + ORD_OFF);

    (void)hipMemsetAsync(grid, 0xFF, (size_t)GRID_CELLS * sizeof(int), stream);
    scatter_kernel<<<(n + 255) / 256, 256, 0, stream>>>(coords, grid, n);
    wfrag_kernel<<<(NTAPS * 2 * 4 * 64 + 255) / 256, 256, 0, stream>>>(weight, wt8);
    count_kernel<<<NCBLK, 256, 0, stream>>>(grid, bcnt);
    scan_kernel<<<1, 1024, 0, stream>>>(bcnt);
    emit_kernel<<<NCBLK, 256, 0, stream>>>(grid, bcnt, order);
    conv_kernel<<<(n + 63) / 64, 256, 0, stream>>>(
        feats, wt8, bias, coords, grid, order, out, n);
}